// Round 1
// baseline (1989.055 us; speedup 1.0000x reference)
//
#include <hip/hip_runtime.h>
#include <math.h>

#define N_IN   128
#define HC     128   // HEADS*OUT_CH
#define HEADS  4
#define NPB    32    // nodes per block in GEMM

// order-preserving float<->uint encoding for atomicMax on floats
__device__ __forceinline__ unsigned encf(float f) {
    unsigned u = __float_as_uint(f);
    return (u & 0x80000000u) ? ~u : (u | 0x80000000u);
}
__device__ __forceinline__ float decf(unsigned u) {
    return (u & 0x80000000u) ? __uint_as_float(u ^ 0x80000000u)
                             : __uint_as_float(~u);
}

// h_src = x @ W_src, h_dst = x @ W_dst   (both [N,128]@[128,128])
__global__ __launch_bounds__(256) void k_gemm(const float* __restrict__ x,
        const float* __restrict__ Ws, const float* __restrict__ Wd,
        float* __restrict__ hs, float* __restrict__ hd, int N) {
    __shared__ float xs[NPB][N_IN];
    int nbase = blockIdx.x * NPB;
    for (int i = threadIdx.x; i < NPB * N_IN; i += 256) {
        int n = nbase + (i >> 7);
        xs[i >> 7][i & 127] = (n < N) ? x[(size_t)n * N_IN + (i & 127)] : 0.f;
    }
    __syncthreads();
    int cg = threadIdx.x & 63;       // channel group: 4 consecutive out channels
    int ng = threadIdx.x >> 6;       // node group: 8 nodes
    const float* W = (cg < 32) ? Ws : Wd;
    float* outp   = (cg < 32) ? hs : hd;
    int c = (cg & 31) * 4;
    float acc[8][4];
#pragma unroll
    for (int n = 0; n < 8; n++) { acc[n][0]=0.f; acc[n][1]=0.f; acc[n][2]=0.f; acc[n][3]=0.f; }
    for (int k = 0; k < N_IN; k++) {
        float4 w = *reinterpret_cast<const float4*>(&W[k * HC + c]);
#pragma unroll
        for (int n = 0; n < 8; n++) {
            float xv = xs[ng * 8 + n][k];
            acc[n][0] += xv * w.x;
            acc[n][1] += xv * w.y;
            acc[n][2] += xv * w.z;
            acc[n][3] += xv * w.w;
        }
    }
#pragma unroll
    for (int n = 0; n < 8; n++) {
        int node = nbase + ng * 8 + n;
        if (node < N)
            *reinterpret_cast<float4*>(&outp[(size_t)node * HC + c]) =
                make_float4(acc[n][0], acc[n][1], acc[n][2], acc[n][3]);
    }
}

// edge pass 1: logits + segment max.  one wave per edge, lane -> 2 channels
__global__ __launch_bounds__(256) void k_logits(const float* __restrict__ hs,
        const float* __restrict__ hd, const int* __restrict__ ei,
        const float* __restrict__ att, float* __restrict__ logits,
        unsigned* __restrict__ nmax, int E, int ET) {
    int wave = threadIdx.x >> 6, lane = threadIdx.x & 63;
    int e = blockIdx.x * 4 + wave;
    if (e >= ET) return;
    int s, d;
    if (e < E) { s = ei[e]; d = ei[E + e]; } else { s = e - E; d = s; }
    int c2 = lane * 2;
    float2 a  = *reinterpret_cast<const float2*>(&hs[(size_t)s * HC + c2]);
    float2 b  = *reinterpret_cast<const float2*>(&hd[(size_t)d * HC + c2]);
    float2 at = *reinterpret_cast<const float2*>(&att[c2]);
    float v0 = a.x + b.x; v0 = (v0 > 0.f) ? v0 : 0.2f * v0;
    float v1 = a.y + b.y; v1 = (v1 > 0.f) ? v1 : 0.2f * v1;
    float p = v0 * at.x + v1 * at.y;
    p += __shfl_xor(p, 1);
    p += __shfl_xor(p, 2);
    p += __shfl_xor(p, 4);
    p += __shfl_xor(p, 8);
    if ((lane & 15) == 0) {
        int h = lane >> 4;
        logits[(size_t)e * HEADS + h] = p;
        atomicMax(&nmax[(size_t)d * HEADS + h], encf(p));
    }
}

// edge pass 2: ex = exp(logit - max); nsum[d] += ex; out[d] += ex * h_src[s]
__global__ __launch_bounds__(256) void k_agg(const float* __restrict__ hs,
        const int* __restrict__ ei, const float* __restrict__ logits,
        const unsigned* __restrict__ nmax, float* __restrict__ nsum,
        float* __restrict__ out, int E, int ET) {
    int wave = threadIdx.x >> 6, lane = threadIdx.x & 63;
    int e = blockIdx.x * 4 + wave;
    if (e >= ET) return;
    int s, d;
    if (e < E) { s = ei[e]; d = ei[E + e]; } else { s = e - E; d = s; }
    int h = lane >> 4;
    float lg = logits[(size_t)e * HEADS + h];
    float m  = decf(nmax[(size_t)d * HEADS + h]);
    float ex = __expf(lg - m);
    if ((lane & 15) == 0) atomicAdd(&nsum[(size_t)d * HEADS + h], ex);
    int c2 = lane * 2;
    float2 v = *reinterpret_cast<const float2*>(&hs[(size_t)s * HC + c2]);
    atomicAdd(&out[(size_t)d * HC + c2],     ex * v.x);
    atomicAdd(&out[(size_t)d * HC + c2 + 1], ex * v.y);
}

// per-channel sum & sumsq of pre-BN values (out/denom)
__global__ __launch_bounds__(256) void k_stats(const float* __restrict__ out,
        const float* __restrict__ nsum, float* __restrict__ stats, int N) {
    int ch = threadIdx.x & 127;
    int half = threadIdx.x >> 7;
    float s = 0.f, s2 = 0.f;
    for (int n = blockIdx.x * 2 + half; n < N; n += gridDim.x * 2) {
        float v = out[(size_t)n * HC + ch] / nsum[n * HEADS + (ch >> 5)];
        s += v; s2 += v * v;
    }
    __shared__ float sh[2][256];
    sh[0][threadIdx.x] = s; sh[1][threadIdx.x] = s2;
    __syncthreads();
    if (threadIdx.x < 128) {
        atomicAdd(&stats[ch],      sh[0][threadIdx.x] + sh[0][threadIdx.x + 128]);
        atomicAdd(&stats[HC + ch], sh[1][threadIdx.x] + sh[1][threadIdx.x + 128]);
    }
}

// fold stats into scale/shift
__global__ void k_bnparams(const float* __restrict__ stats,
        const float* __restrict__ gamma, const float* __restrict__ beta,
        float* __restrict__ ss, int N) {
    int c = threadIdx.x;
    if (c >= HC) return;
    float mean = stats[c] / (float)N;
    float var  = stats[HC + c] / (float)N - mean * mean;
    float sc = gamma[c] * rsqrtf(var + 1e-5f);
    ss[c]      = sc;
    ss[HC + c] = beta[c] - mean * sc;
}

// finalize: divide by denom, BN affine, leaky(0.02)
__global__ __launch_bounds__(256) void k_final(float* __restrict__ out,
        const float* __restrict__ nsum, const float* __restrict__ ss, int total) {
    int i = blockIdx.x * 256 + threadIdx.x;
    if (i >= total) return;
    int c = i & 127, n = i >> 7;
    float v = out[i] / nsum[n * HEADS + (c >> 5)];
    float y = v * ss[c] + ss[HC + c];
    out[i] = (y > 0.f) ? y : 0.02f * y;
}

extern "C" void kernel_launch(void* const* d_in, const int* in_sizes, int n_in,
                              void* d_out, int out_size, void* d_ws, size_t ws_size,
                              hipStream_t stream) {
    const float* x     = (const float*)d_in[0];
    const int*   ei    = (const int*)d_in[1];
    const float* Ws    = (const float*)d_in[2];
    const float* Wd    = (const float*)d_in[3];
    const float* att   = (const float*)d_in[4];
    // d_in[5] = bias: cancels exactly inside BatchNorm (shifts mean equally) -> skipped
    const float* gamma = (const float*)d_in[6];
    const float* beta  = (const float*)d_in[7];
    float* out = (float*)d_out;

    int N  = in_sizes[0] / N_IN;
    int E  = in_sizes[1] / 2;
    int ET = E + N;

    char* ws = (char*)d_ws;
    float* hs       = (float*)ws; ws += (size_t)N * HC * 4;
    float* hd       = (float*)ws; ws += (size_t)N * HC * 4;
    float* logits   = (float*)ws; ws += (size_t)ET * HEADS * 4;
    unsigned* nmax  = (unsigned*)ws; ws += (size_t)N * HEADS * 4;
    float* nsum     = (float*)ws; ws += (size_t)N * HEADS * 4;
    float* stats    = (float*)ws; ws += 2 * HC * 4;
    float* ss       = (float*)ws; ws += 2 * HC * 4;

    hipMemsetAsync(d_out, 0, (size_t)N * HC * 4, stream);
    hipMemsetAsync(nmax, 0, (size_t)N * HEADS * 4, stream);   // enc(-inf) ~ 0
    hipMemsetAsync(nsum, 0, (size_t)N * HEADS * 4, stream);
    hipMemsetAsync(stats, 0, 2 * HC * 4, stream);

    k_gemm<<<(N + NPB - 1) / NPB, 256, 0, stream>>>(x, Ws, Wd, hs, hd, N);
    k_logits<<<(ET + 3) / 4, 256, 0, stream>>>(hs, hd, ei, att, logits, nmax, E, ET);
    k_agg<<<(ET + 3) / 4, 256, 0, stream>>>(hs, ei, logits, nmax, nsum, out, E, ET);
    k_stats<<<1024, 256, 0, stream>>>(out, nsum, stats, N);
    k_bnparams<<<1, 128, 0, stream>>>(stats, gamma, beta, ss, N);
    k_final<<<(N * HC + 255) / 256, 256, 0, stream>>>(out, nsum, ss, N * HC);
}

// Round 2
// 794.191 us; speedup vs baseline: 2.5045x; 2.5045x over previous
//
#include <hip/hip_runtime.h>
#include <math.h>

#define N_IN   128
#define HC     128   // HEADS*OUT_CH
#define HEADS  4
#define NPB    32    // nodes per block in GEMM
#define SCAN_T 1024

// h_src = x @ W_src, h_dst = x @ W_dst   (both [N,128]@[128,128])
__global__ __launch_bounds__(256) void k_gemm(const float* __restrict__ x,
        const float* __restrict__ Ws, const float* __restrict__ Wd,
        float* __restrict__ hs, float* __restrict__ hd, int N) {
    __shared__ float xs[NPB][N_IN];
    int nbase = blockIdx.x * NPB;
    for (int i = threadIdx.x; i < NPB * N_IN; i += 256) {
        int n = nbase + (i >> 7);
        xs[i >> 7][i & 127] = (n < N) ? x[(size_t)n * N_IN + (i & 127)] : 0.f;
    }
    __syncthreads();
    int cg = threadIdx.x & 63;       // channel group: 4 consecutive out channels
    int ng = threadIdx.x >> 6;       // node group: 8 nodes
    const float* W = (cg < 32) ? Ws : Wd;
    float* outp   = (cg < 32) ? hs : hd;
    int c = (cg & 31) * 4;
    float acc[8][4];
#pragma unroll
    for (int n = 0; n < 8; n++) { acc[n][0]=0.f; acc[n][1]=0.f; acc[n][2]=0.f; acc[n][3]=0.f; }
    for (int k = 0; k < N_IN; k++) {
        float4 w = *reinterpret_cast<const float4*>(&W[k * HC + c]);
#pragma unroll
        for (int n = 0; n < 8; n++) {
            float xv = xs[ng * 8 + n][k];
            acc[n][0] += xv * w.x;
            acc[n][1] += xv * w.y;
            acc[n][2] += xv * w.z;
            acc[n][3] += xv * w.w;
        }
    }
#pragma unroll
    for (int n = 0; n < 8; n++) {
        int node = nbase + ng * 8 + n;
        if (node < N)
            *reinterpret_cast<float4*>(&outp[(size_t)node * HC + c]) =
                make_float4(acc[n][0], acc[n][1], acc[n][2], acc[n][3]);
    }
}

// in-degree histogram
__global__ __launch_bounds__(256) void k_hist(const int* __restrict__ ei,
        int* __restrict__ deg, int E) {
    int e = blockIdx.x * 256 + threadIdx.x;
    if (e < E) atomicAdd(&deg[ei[E + e]], 1);
}

// single-block exclusive scan of deg -> off (and a scatter cursor copy)
__global__ __launch_bounds__(SCAN_T) void k_scan(const int* __restrict__ deg,
        int* __restrict__ off, int* __restrict__ cur, int N) {
    __shared__ int sh[SCAN_T];
    int t = threadIdx.x;
    int per = (N + SCAN_T - 1) / SCAN_T;
    int b = t * per;
    int e = min(b + per, N);
    int s = 0;
    for (int i = b; i < e; i++) s += deg[i];
    sh[t] = s;
    __syncthreads();
    for (int ofs = 1; ofs < SCAN_T; ofs <<= 1) {
        int add = (t >= ofs) ? sh[t - ofs] : 0;
        __syncthreads();
        sh[t] += add;
        __syncthreads();
    }
    int running = (t == 0) ? 0 : sh[t - 1];
    for (int i = b; i < e; i++) {
        off[i] = running;
        cur[i] = running;
        running += deg[i];
    }
}

// bucket source ids by destination
__global__ __launch_bounds__(256) void k_scatter(const int* __restrict__ ei,
        int* __restrict__ cur, int* __restrict__ ssrc, int E) {
    int e = blockIdx.x * 256 + threadIdx.x;
    if (e < E) {
        int d = ei[E + e];
        int pos = atomicAdd(&cur[d], 1);
        ssrc[pos] = ei[e];
    }
}

// fused per-node aggregation: online softmax over incoming edges, no atomics.
// one wave per node; lane -> 2 channels; head = lane>>4.
__global__ __launch_bounds__(256) void k_agg2(const float* __restrict__ hs,
        const float* __restrict__ hd, const int* __restrict__ off,
        const int* __restrict__ deg, const int* __restrict__ ssrc,
        const float* __restrict__ att, float* __restrict__ out, int N) {
    int wid = (blockIdx.x * 256 + threadIdx.x) >> 6;
    int lane = threadIdx.x & 63;
    if (wid >= N) return;
    int d = wid;
    int c2 = lane * 2;
    float2 at  = *reinterpret_cast<const float2*>(&att[c2]);
    float2 hdv = *reinterpret_cast<const float2*>(&hd[(size_t)d * HC + c2]);
    // self-loop initializes the online softmax
    float2 v = *reinterpret_cast<const float2*>(&hs[(size_t)d * HC + c2]);
    float t0 = v.x + hdv.x; t0 = (t0 > 0.f) ? t0 : 0.2f * t0;
    float t1 = v.y + hdv.y; t1 = (t1 > 0.f) ? t1 : 0.2f * t1;
    float p = t0 * at.x + t1 * at.y;
    p += __shfl_xor(p, 1); p += __shfl_xor(p, 2);
    p += __shfl_xor(p, 4); p += __shfl_xor(p, 8);
    float m = p, ssum = 1.f;
    float2 acc = v;
    int beg = off[d], end = beg + deg[d];
    for (int i = beg; i < end; i++) {
        int s = ssrc[i];
        v = *reinterpret_cast<const float2*>(&hs[(size_t)s * HC + c2]);
        t0 = v.x + hdv.x; t0 = (t0 > 0.f) ? t0 : 0.2f * t0;
        t1 = v.y + hdv.y; t1 = (t1 > 0.f) ? t1 : 0.2f * t1;
        p = t0 * at.x + t1 * at.y;
        p += __shfl_xor(p, 1); p += __shfl_xor(p, 2);
        p += __shfl_xor(p, 4); p += __shfl_xor(p, 8);
        if (p > m) {
            float r = __expf(m - p);
            ssum *= r; acc.x *= r; acc.y *= r; m = p;
        }
        float ex = __expf(p - m);
        ssum += ex;
        acc.x += ex * v.x;
        acc.y += ex * v.y;
    }
    float inv = 1.f / ssum;
    *reinterpret_cast<float2*>(&out[(size_t)d * HC + c2]) =
        make_float2(acc.x * inv, acc.y * inv);
}

// per-channel sum & sumsq of pre-BN values
__global__ __launch_bounds__(256) void k_stats(const float* __restrict__ out,
        float* __restrict__ stats, int N) {
    int ch = threadIdx.x & 127;
    int half = threadIdx.x >> 7;
    float s = 0.f, s2 = 0.f;
    for (int n = blockIdx.x * 2 + half; n < N; n += gridDim.x * 2) {
        float v = out[(size_t)n * HC + ch];
        s += v; s2 += v * v;
    }
    __shared__ float sh[2][256];
    sh[0][threadIdx.x] = s; sh[1][threadIdx.x] = s2;
    __syncthreads();
    if (threadIdx.x < 128) {
        atomicAdd(&stats[ch],      sh[0][threadIdx.x] + sh[0][threadIdx.x + 128]);
        atomicAdd(&stats[HC + ch], sh[1][threadIdx.x] + sh[1][threadIdx.x + 128]);
    }
}

// fold stats into scale/shift
__global__ void k_bnparams(const float* __restrict__ stats,
        const float* __restrict__ gamma, const float* __restrict__ beta,
        float* __restrict__ ss, int N) {
    int c = threadIdx.x;
    if (c >= HC) return;
    float mean = stats[c] / (float)N;
    float var  = stats[HC + c] / (float)N - mean * mean;
    float sc = gamma[c] * rsqrtf(var + 1e-5f);
    ss[c]      = sc;
    ss[HC + c] = beta[c] - mean * sc;
}

// finalize: BN affine + leaky(0.02), in place
__global__ __launch_bounds__(256) void k_final(float* __restrict__ out,
        const float* __restrict__ ss, int total) {
    int i = blockIdx.x * 256 + threadIdx.x;
    if (i >= total) return;
    int c = i & 127;
    float y = out[i] * ss[c] + ss[HC + c];
    out[i] = (y > 0.f) ? y : 0.02f * y;
}

extern "C" void kernel_launch(void* const* d_in, const int* in_sizes, int n_in,
                              void* d_out, int out_size, void* d_ws, size_t ws_size,
                              hipStream_t stream) {
    const float* x     = (const float*)d_in[0];
    const int*   ei    = (const int*)d_in[1];
    const float* Ws    = (const float*)d_in[2];
    const float* Wd    = (const float*)d_in[3];
    const float* att   = (const float*)d_in[4];
    // d_in[5] = bias: cancels exactly inside BatchNorm -> skipped
    const float* gamma = (const float*)d_in[6];
    const float* beta  = (const float*)d_in[7];
    float* out = (float*)d_out;

    int N  = in_sizes[0] / N_IN;
    int E  = in_sizes[1] / 2;

    char* ws = (char*)d_ws;
    float* hs   = (float*)ws; ws += (size_t)N * HC * 4;
    float* hd   = (float*)ws; ws += (size_t)N * HC * 4;
    int* deg    = (int*)ws;   ws += (size_t)N * 4;
    int* off    = (int*)ws;   ws += (size_t)N * 4;
    int* cur    = (int*)ws;   ws += (size_t)N * 4;
    int* ssrc   = (int*)ws;   ws += (size_t)E * 4;
    float* stats= (float*)ws; ws += 2 * HC * 4;
    float* ss   = (float*)ws; ws += 2 * HC * 4;

    hipMemsetAsync(deg, 0, (size_t)N * 4, stream);
    hipMemsetAsync(stats, 0, 2 * HC * 4, stream);

    k_gemm<<<(N + NPB - 1) / NPB, 256, 0, stream>>>(x, Ws, Wd, hs, hd, N);
    k_hist<<<(E + 255) / 256, 256, 0, stream>>>(ei, deg, E);
    k_scan<<<1, SCAN_T, 0, stream>>>(deg, off, cur, N);
    k_scatter<<<(E + 255) / 256, 256, 0, stream>>>(ei, cur, ssrc, E);
    k_agg2<<<(N * 64 + 255) / 256, 256, 0, stream>>>(hs, hd, off, deg, ssrc, att, out, N);
    k_stats<<<1024, 256, 0, stream>>>(out, stats, N);
    k_bnparams<<<1, 128, 0, stream>>>(stats, gamma, beta, ss, N);
    k_final<<<(N * HC + 255) / 256, 256, 0, stream>>>(out, ss, N * HC);
}

// Round 3
// 580.696 us; speedup vs baseline: 3.4253x; 1.3677x over previous
//
#include <hip/hip_runtime.h>
#include <math.h>

#define N_IN   128
#define HC     128   // HEADS*OUT_CH
#define HEADS  4
#define NPB    32    // nodes per block in GEMM
#define CHUNK  1024  // scan elements per block (256 thr x 4)

// h_src = x @ W_src, h_dst = x @ W_dst   (both [N,128]@[128,128])
__global__ __launch_bounds__(256) void k_gemm(const float* __restrict__ x,
        const float* __restrict__ Ws, const float* __restrict__ Wd,
        float* __restrict__ hs, float* __restrict__ hd, int N) {
    __shared__ float xs[NPB][N_IN];
    int nbase = blockIdx.x * NPB;
    for (int i = threadIdx.x; i < NPB * N_IN; i += 256) {
        int n = nbase + (i >> 7);
        xs[i >> 7][i & 127] = (n < N) ? x[(size_t)n * N_IN + (i & 127)] : 0.f;
    }
    __syncthreads();
    int cg = threadIdx.x & 63;       // channel group: 4 consecutive out channels
    int ng = threadIdx.x >> 6;       // node group: 8 nodes
    const float* W = (cg < 32) ? Ws : Wd;
    float* outp   = (cg < 32) ? hs : hd;
    int c = (cg & 31) * 4;
    float acc[8][4];
#pragma unroll
    for (int n = 0; n < 8; n++) { acc[n][0]=0.f; acc[n][1]=0.f; acc[n][2]=0.f; acc[n][3]=0.f; }
    for (int k = 0; k < N_IN; k++) {
        float4 w = *reinterpret_cast<const float4*>(&W[k * HC + c]);
#pragma unroll
        for (int n = 0; n < 8; n++) {
            float xv = xs[ng * 8 + n][k];
            acc[n][0] += xv * w.x;
            acc[n][1] += xv * w.y;
            acc[n][2] += xv * w.z;
            acc[n][3] += xv * w.w;
        }
    }
#pragma unroll
    for (int n = 0; n < 8; n++) {
        int node = nbase + ng * 8 + n;
        if (node < N)
            *reinterpret_cast<float4*>(&outp[(size_t)node * HC + c]) =
                make_float4(acc[n][0], acc[n][1], acc[n][2], acc[n][3]);
    }
}

// in-degree histogram
__global__ __launch_bounds__(256) void k_hist(const int* __restrict__ ei,
        int* __restrict__ deg, int E) {
    int e = blockIdx.x * 256 + threadIdx.x;
    if (e < E) atomicAdd(&deg[ei[E + e]], 1);
}

// scan phase 1: per-block (1024-elem chunk) sum
__global__ __launch_bounds__(256) void k_scan_part(const int* __restrict__ deg,
        int* __restrict__ bsum, int N) {
    __shared__ int sh[256];
    int base = blockIdx.x * CHUNK + threadIdx.x * 4;
    int s = 0;
#pragma unroll
    for (int i = 0; i < 4; i++) s += (base + i < N) ? deg[base + i] : 0;
    sh[threadIdx.x] = s;
    __syncthreads();
    for (int ofs = 128; ofs > 0; ofs >>= 1) {
        if (threadIdx.x < ofs) sh[threadIdx.x] += sh[threadIdx.x + ofs];
        __syncthreads();
    }
    if (threadIdx.x == 0) bsum[blockIdx.x] = sh[0];
}

// scan phase 2: exclusive scan of block sums (single block, up to 1024 blocks)
__global__ __launch_bounds__(1024) void k_scan_mid(const int* __restrict__ bsum,
        int* __restrict__ bsumx, int B) {
    __shared__ int sh[1024];
    int t = threadIdx.x;
    int v = (t < B) ? bsum[t] : 0;
    sh[t] = v;
    __syncthreads();
    for (int ofs = 1; ofs < 1024; ofs <<= 1) {
        int add = (t >= ofs) ? sh[t - ofs] : 0;
        __syncthreads();
        sh[t] += add;
        __syncthreads();
    }
    if (t < B) bsumx[t] = sh[t] - v;   // exclusive
}

// scan phase 3: local prefix + block offset -> off, cur
__global__ __launch_bounds__(256) void k_scan_add(const int* __restrict__ deg,
        const int* __restrict__ bsumx, int* __restrict__ off,
        int* __restrict__ cur, int N) {
    __shared__ int sh[256];
    int t = threadIdx.x;
    int base = blockIdx.x * CHUNK + t * 4;
    int v0 = (base + 0 < N) ? deg[base + 0] : 0;
    int v1 = (base + 1 < N) ? deg[base + 1] : 0;
    int v2 = (base + 2 < N) ? deg[base + 2] : 0;
    int v3 = (base + 3 < N) ? deg[base + 3] : 0;
    int tot = v0 + v1 + v2 + v3;
    sh[t] = tot;
    __syncthreads();
    for (int ofs = 1; ofs < 256; ofs <<= 1) {
        int add = (t >= ofs) ? sh[t - ofs] : 0;
        __syncthreads();
        sh[t] += add;
        __syncthreads();
    }
    int run = sh[t] - tot + bsumx[blockIdx.x];   // exclusive base for this thread
    int p0 = run, p1 = run + v0, p2 = p1 + v1, p3 = p2 + v2;
    if (base + 0 < N) { off[base + 0] = p0; cur[base + 0] = p0; }
    if (base + 1 < N) { off[base + 1] = p1; cur[base + 1] = p1; }
    if (base + 2 < N) { off[base + 2] = p2; cur[base + 2] = p2; }
    if (base + 3 < N) { off[base + 3] = p3; cur[base + 3] = p3; }
}

// bucket source ids by destination
__global__ __launch_bounds__(256) void k_scatter(const int* __restrict__ ei,
        int* __restrict__ cur, int* __restrict__ ssrc, int E) {
    int e = blockIdx.x * 256 + threadIdx.x;
    if (e < E) {
        int d = ei[E + e];
        int pos = atomicAdd(&cur[d], 1);
        ssrc[pos] = ei[e];
    }
}

// fused per-node aggregation: online softmax over incoming edges, no atomics.
// one wave per node; lane -> 2 channels; head = lane>>4.
__global__ __launch_bounds__(256) void k_agg2(const float* __restrict__ hs,
        const float* __restrict__ hd, const int* __restrict__ off,
        const int* __restrict__ deg, const int* __restrict__ ssrc,
        const float* __restrict__ att, float* __restrict__ out, int N) {
    int wid = (blockIdx.x * 256 + threadIdx.x) >> 6;
    int lane = threadIdx.x & 63;
    if (wid >= N) return;
    int d = wid;
    int c2 = lane * 2;
    float2 at  = *reinterpret_cast<const float2*>(&att[c2]);
    float2 hdv = *reinterpret_cast<const float2*>(&hd[(size_t)d * HC + c2]);
    // self-loop initializes the online softmax
    float2 v = *reinterpret_cast<const float2*>(&hs[(size_t)d * HC + c2]);
    float t0 = v.x + hdv.x; t0 = (t0 > 0.f) ? t0 : 0.2f * t0;
    float t1 = v.y + hdv.y; t1 = (t1 > 0.f) ? t1 : 0.2f * t1;
    float p = t0 * at.x + t1 * at.y;
    p += __shfl_xor(p, 1); p += __shfl_xor(p, 2);
    p += __shfl_xor(p, 4); p += __shfl_xor(p, 8);
    float m = p, ssum = 1.f;
    float2 acc = v;
    int beg = off[d], end = beg + deg[d];
    for (int i = beg; i < end; i++) {
        int s = ssrc[i];
        v = *reinterpret_cast<const float2*>(&hs[(size_t)s * HC + c2]);
        t0 = v.x + hdv.x; t0 = (t0 > 0.f) ? t0 : 0.2f * t0;
        t1 = v.y + hdv.y; t1 = (t1 > 0.f) ? t1 : 0.2f * t1;
        p = t0 * at.x + t1 * at.y;
        p += __shfl_xor(p, 1); p += __shfl_xor(p, 2);
        p += __shfl_xor(p, 4); p += __shfl_xor(p, 8);
        if (p > m) {
            float r = __expf(m - p);
            ssum *= r; acc.x *= r; acc.y *= r; m = p;
        }
        float ex = __expf(p - m);
        ssum += ex;
        acc.x += ex * v.x;
        acc.y += ex * v.y;
    }
    float inv = 1.f / ssum;
    *reinterpret_cast<float2*>(&out[(size_t)d * HC + c2]) =
        make_float2(acc.x * inv, acc.y * inv);
}

// per-channel sum & sumsq of pre-BN values
__global__ __launch_bounds__(256) void k_stats(const float* __restrict__ out,
        float* __restrict__ stats, int N) {
    int ch = threadIdx.x & 127;
    int half = threadIdx.x >> 7;
    float s = 0.f, s2 = 0.f;
    for (int n = blockIdx.x * 2 + half; n < N; n += gridDim.x * 2) {
        float v = out[(size_t)n * HC + ch];
        s += v; s2 += v * v;
    }
    __shared__ float sh[2][256];
    sh[0][threadIdx.x] = s; sh[1][threadIdx.x] = s2;
    __syncthreads();
    if (threadIdx.x < 128) {
        atomicAdd(&stats[ch],      sh[0][threadIdx.x] + sh[0][threadIdx.x + 128]);
        atomicAdd(&stats[HC + ch], sh[1][threadIdx.x] + sh[1][threadIdx.x + 128]);
    }
}

// fold stats into scale/shift
__global__ void k_bnparams(const float* __restrict__ stats,
        const float* __restrict__ gamma, const float* __restrict__ beta,
        float* __restrict__ ss, int N) {
    int c = threadIdx.x;
    if (c >= HC) return;
    float mean = stats[c] / (float)N;
    float var  = stats[HC + c] / (float)N - mean * mean;
    float sc = gamma[c] * rsqrtf(var + 1e-5f);
    ss[c]      = sc;
    ss[HC + c] = beta[c] - mean * sc;
}

// finalize: BN affine + leaky(0.02), in place
__global__ __launch_bounds__(256) void k_final(float* __restrict__ out,
        const float* __restrict__ ss, int total) {
    int i = blockIdx.x * 256 + threadIdx.x;
    if (i >= total) return;
    int c = i & 127;
    float y = out[i] * ss[c] + ss[HC + c];
    out[i] = (y > 0.f) ? y : 0.02f * y;
}

extern "C" void kernel_launch(void* const* d_in, const int* in_sizes, int n_in,
                              void* d_out, int out_size, void* d_ws, size_t ws_size,
                              hipStream_t stream) {
    const float* x     = (const float*)d_in[0];
    const int*   ei    = (const int*)d_in[1];
    const float* Ws    = (const float*)d_in[2];
    const float* Wd    = (const float*)d_in[3];
    const float* att   = (const float*)d_in[4];
    // d_in[5] = bias: cancels exactly inside BatchNorm -> skipped
    const float* gamma = (const float*)d_in[6];
    const float* beta  = (const float*)d_in[7];
    float* out = (float*)d_out;

    int N  = in_sizes[0] / N_IN;
    int E  = in_sizes[1] / 2;
    int B  = (N + CHUNK - 1) / CHUNK;   // scan blocks (<=1024 supported)

    char* ws = (char*)d_ws;
    float* hs   = (float*)ws; ws += (size_t)N * HC * 4;
    float* hd   = (float*)ws; ws += (size_t)N * HC * 4;
    int* deg    = (int*)ws;   ws += (size_t)N * 4;
    int* off    = (int*)ws;   ws += (size_t)N * 4;
    int* cur    = (int*)ws;   ws += (size_t)N * 4;
    int* ssrc   = (int*)ws;   ws += (size_t)E * 4;
    int* bsum   = (int*)ws;   ws += 1024 * 4;
    int* bsumx  = (int*)ws;   ws += 1024 * 4;
    float* stats= (float*)ws; ws += 2 * HC * 4;
    float* ss   = (float*)ws; ws += 2 * HC * 4;

    hipMemsetAsync(deg, 0, (size_t)N * 4, stream);
    hipMemsetAsync(stats, 0, 2 * HC * 4, stream);

    k_gemm<<<(N + NPB - 1) / NPB, 256, 0, stream>>>(x, Ws, Wd, hs, hd, N);
    k_hist<<<(E + 255) / 256, 256, 0, stream>>>(ei, deg, E);
    k_scan_part<<<B, 256, 0, stream>>>(deg, bsum, N);
    k_scan_mid<<<1, 1024, 0, stream>>>(bsum, bsumx, B);
    k_scan_add<<<B, 256, 0, stream>>>(deg, bsumx, off, cur, N);
    k_scatter<<<(E + 255) / 256, 256, 0, stream>>>(ei, cur, ssrc, E);
    k_agg2<<<(N * 64 + 255) / 256, 256, 0, stream>>>(hs, hd, off, deg, ssrc, att, out, N);
    k_stats<<<1024, 256, 0, stream>>>(out, stats, N);
    k_bnparams<<<1, 128, 0, stream>>>(stats, gamma, beta, ss, N);
    k_final<<<(N * HC + 255) / 256, 256, 0, stream>>>(out, ss, N * HC);
}

// Round 4
// 480.785 us; speedup vs baseline: 4.1371x; 1.2078x over previous
//
#include <hip/hip_runtime.h>
#include <math.h>

#define N_IN   128
#define HC     128   // HEADS*OUT_CH
#define HEADS  4
#define NPB    32    // nodes per block in GEMM
#define CHUNK  1024  // scan elements per block (256 thr x 4)

// bf16 helpers: exact decode, RNE encode
__device__ __forceinline__ unsigned short f2bf(float f) {
    unsigned u = __float_as_uint(f);
    return (unsigned short)((u + 0x7FFFu + ((u >> 16) & 1u)) >> 16);
}
__device__ __forceinline__ float2 ldbf2(const unsigned short* p) {
    ushort2 u = *reinterpret_cast<const ushort2*>(p);
    float2 r;
    r.x = __uint_as_float((unsigned)u.x << 16);
    r.y = __uint_as_float((unsigned)u.y << 16);
    return r;
}

// h_src = x @ W_src (bf16 out), h_dst = x @ W_dst (fp32 out)
__global__ __launch_bounds__(256) void k_gemm(const float* __restrict__ x,
        const float* __restrict__ Ws, const float* __restrict__ Wd,
        unsigned short* __restrict__ hs, float* __restrict__ hd, int N) {
    __shared__ float xs[NPB][N_IN];
    int nbase = blockIdx.x * NPB;
    for (int i = threadIdx.x; i < NPB * N_IN; i += 256) {
        int n = nbase + (i >> 7);
        xs[i >> 7][i & 127] = (n < N) ? x[(size_t)n * N_IN + (i & 127)] : 0.f;
    }
    __syncthreads();
    int cg = threadIdx.x & 63;       // channel group: 4 consecutive out channels
    int ng = threadIdx.x >> 6;       // node group: 8 nodes
    bool is_src = (cg < 32);
    const float* W = is_src ? Ws : Wd;
    int c = (cg & 31) * 4;
    float acc[8][4];
#pragma unroll
    for (int n = 0; n < 8; n++) { acc[n][0]=0.f; acc[n][1]=0.f; acc[n][2]=0.f; acc[n][3]=0.f; }
    for (int k = 0; k < N_IN; k++) {
        float4 w = *reinterpret_cast<const float4*>(&W[k * HC + c]);
#pragma unroll
        for (int n = 0; n < 8; n++) {
            float xv = xs[ng * 8 + n][k];
            acc[n][0] += xv * w.x;
            acc[n][1] += xv * w.y;
            acc[n][2] += xv * w.z;
            acc[n][3] += xv * w.w;
        }
    }
#pragma unroll
    for (int n = 0; n < 8; n++) {
        int node = nbase + ng * 8 + n;
        if (node < N) {
            if (is_src) {
                ushort4 b = make_ushort4(f2bf(acc[n][0]), f2bf(acc[n][1]),
                                         f2bf(acc[n][2]), f2bf(acc[n][3]));
                *reinterpret_cast<ushort4*>(&hs[(size_t)node * HC + c]) = b;
            } else {
                *reinterpret_cast<float4*>(&hd[(size_t)node * HC + c]) =
                    make_float4(acc[n][0], acc[n][1], acc[n][2], acc[n][3]);
            }
        }
    }
}

// in-degree histogram
__global__ __launch_bounds__(256) void k_hist(const int* __restrict__ ei,
        int* __restrict__ deg, int E) {
    int e = blockIdx.x * 256 + threadIdx.x;
    if (e < E) atomicAdd(&deg[ei[E + e]], 1);
}

// scan phase 1: per-block (1024-elem chunk) sum
__global__ __launch_bounds__(256) void k_scan_part(const int* __restrict__ deg,
        int* __restrict__ bsum, int N) {
    __shared__ int sh[256];
    int base = blockIdx.x * CHUNK + threadIdx.x * 4;
    int s = 0;
#pragma unroll
    for (int i = 0; i < 4; i++) s += (base + i < N) ? deg[base + i] : 0;
    sh[threadIdx.x] = s;
    __syncthreads();
    for (int ofs = 128; ofs > 0; ofs >>= 1) {
        if (threadIdx.x < ofs) sh[threadIdx.x] += sh[threadIdx.x + ofs];
        __syncthreads();
    }
    if (threadIdx.x == 0) bsum[blockIdx.x] = sh[0];
}

// scan phase 2: exclusive scan of block sums (single block)
__global__ __launch_bounds__(1024) void k_scan_mid(const int* __restrict__ bsum,
        int* __restrict__ bsumx, int B) {
    __shared__ int sh[1024];
    int t = threadIdx.x;
    int v = (t < B) ? bsum[t] : 0;
    sh[t] = v;
    __syncthreads();
    for (int ofs = 1; ofs < 1024; ofs <<= 1) {
        int add = (t >= ofs) ? sh[t - ofs] : 0;
        __syncthreads();
        sh[t] += add;
        __syncthreads();
    }
    if (t < B) bsumx[t] = sh[t] - v;   // exclusive
}

// scan phase 3: local prefix + block offset -> off, cur
__global__ __launch_bounds__(256) void k_scan_add(const int* __restrict__ deg,
        const int* __restrict__ bsumx, int* __restrict__ off,
        int* __restrict__ cur, int N) {
    __shared__ int sh[256];
    int t = threadIdx.x;
    int base = blockIdx.x * CHUNK + t * 4;
    int v0 = (base + 0 < N) ? deg[base + 0] : 0;
    int v1 = (base + 1 < N) ? deg[base + 1] : 0;
    int v2 = (base + 2 < N) ? deg[base + 2] : 0;
    int v3 = (base + 3 < N) ? deg[base + 3] : 0;
    int tot = v0 + v1 + v2 + v3;
    sh[t] = tot;
    __syncthreads();
    for (int ofs = 1; ofs < 256; ofs <<= 1) {
        int add = (t >= ofs) ? sh[t - ofs] : 0;
        __syncthreads();
        sh[t] += add;
        __syncthreads();
    }
    int run = sh[t] - tot + bsumx[blockIdx.x];
    int p0 = run, p1 = run + v0, p2 = p1 + v1, p3 = p2 + v2;
    if (base + 0 < N) { off[base + 0] = p0; cur[base + 0] = p0; }
    if (base + 1 < N) { off[base + 1] = p1; cur[base + 1] = p1; }
    if (base + 2 < N) { off[base + 2] = p2; cur[base + 2] = p2; }
    if (base + 3 < N) { off[base + 3] = p3; cur[base + 3] = p3; }
}

// bucket source ids by destination
__global__ __launch_bounds__(256) void k_scatter(const int* __restrict__ ei,
        int* __restrict__ cur, int* __restrict__ ssrc, int E) {
    int e = blockIdx.x * 256 + threadIdx.x;
    if (e < E) {
        int d = ei[E + e];
        int pos = atomicAdd(&cur[d], 1);
        ssrc[pos] = ei[e];
    }
}

// ---- fused per-node aggregation --------------------------------------------
__device__ __forceinline__ float edge_logit(float2 v, float2 hdv, float2 at) {
    float t0 = v.x + hdv.x; t0 = (t0 > 0.f) ? t0 : 0.2f * t0;
    float t1 = v.y + hdv.y; t1 = (t1 > 0.f) ? t1 : 0.2f * t1;
    float p = t0 * at.x + t1 * at.y;
    p += __shfl_xor(p, 1); p += __shfl_xor(p, 2);
    p += __shfl_xor(p, 4); p += __shfl_xor(p, 8);
    return p;
}
__device__ __forceinline__ void sm_merge(float2 v, float p,
        float& m, float& ssum, float2& acc) {
    float nm = fmaxf(m, p);
    float r = __expf(m - nm);
    float e = __expf(p - nm);
    ssum = ssum * r + e;
    acc.x = acc.x * r + e * v.x;
    acc.y = acc.y * r + e * v.y;
    m = nm;
}

// one wave per node; lane -> 2 channels; head = lane>>4. bf16 h_src gathers.
__global__ __launch_bounds__(256) void k_agg2(const unsigned short* __restrict__ hs,
        const float* __restrict__ hd, const int* __restrict__ off,
        const int* __restrict__ deg, const int* __restrict__ ssrc,
        const float* __restrict__ att, float* __restrict__ out, int N) {
    int wid = (blockIdx.x * 256 + threadIdx.x) >> 6;
    int lane = threadIdx.x & 63;
    if (wid >= N) return;
    int c2 = lane * 2;
    float2 at  = *reinterpret_cast<const float2*>(&att[c2]);
    float2 hdv = *reinterpret_cast<const float2*>(&hd[(size_t)wid * HC + c2]);
    // self-loop initializes the online softmax
    float2 v = ldbf2(&hs[(size_t)wid * HC + c2]);
    float m = edge_logit(v, hdv, at);
    float ssum = 1.f;
    float2 acc = v;
    int beg = off[wid], end = beg + deg[wid];
    int i = beg;
    for (; i + 3 < end; i += 4) {
        int s0 = ssrc[i], s1 = ssrc[i + 1], s2 = ssrc[i + 2], s3 = ssrc[i + 3];
        float2 v0 = ldbf2(&hs[(size_t)s0 * HC + c2]);
        float2 v1 = ldbf2(&hs[(size_t)s1 * HC + c2]);
        float2 v2 = ldbf2(&hs[(size_t)s2 * HC + c2]);
        float2 v3 = ldbf2(&hs[(size_t)s3 * HC + c2]);
        float p0 = edge_logit(v0, hdv, at);
        float p1 = edge_logit(v1, hdv, at);
        float p2 = edge_logit(v2, hdv, at);
        float p3 = edge_logit(v3, hdv, at);
        sm_merge(v0, p0, m, ssum, acc);
        sm_merge(v1, p1, m, ssum, acc);
        sm_merge(v2, p2, m, ssum, acc);
        sm_merge(v3, p3, m, ssum, acc);
    }
    for (; i < end; i++) {
        int s = ssrc[i];
        float2 ve = ldbf2(&hs[(size_t)s * HC + c2]);
        float pe = edge_logit(ve, hdv, at);
        sm_merge(ve, pe, m, ssum, acc);
    }
    float inv = 1.f / ssum;
    *reinterpret_cast<float2*>(&out[(size_t)wid * HC + c2]) =
        make_float2(acc.x * inv, acc.y * inv);
}

// per-channel sum & sumsq of pre-BN values
__global__ __launch_bounds__(256) void k_stats(const float* __restrict__ out,
        float* __restrict__ stats, int N) {
    int ch = threadIdx.x & 127;
    int half = threadIdx.x >> 7;
    float s = 0.f, s2 = 0.f;
    for (int n = blockIdx.x * 2 + half; n < N; n += gridDim.x * 2) {
        float v = out[(size_t)n * HC + ch];
        s += v; s2 += v * v;
    }
    __shared__ float sh[2][256];
    sh[0][threadIdx.x] = s; sh[1][threadIdx.x] = s2;
    __syncthreads();
    if (threadIdx.x < 128) {
        atomicAdd(&stats[ch],      sh[0][threadIdx.x] + sh[0][threadIdx.x + 128]);
        atomicAdd(&stats[HC + ch], sh[1][threadIdx.x] + sh[1][threadIdx.x + 128]);
    }
}

// fold stats into scale/shift
__global__ void k_bnparams(const float* __restrict__ stats,
        const float* __restrict__ gamma, const float* __restrict__ beta,
        float* __restrict__ ss, int N) {
    int c = threadIdx.x;
    if (c >= HC) return;
    float mean = stats[c] / (float)N;
    float var  = stats[HC + c] / (float)N - mean * mean;
    float sc = gamma[c] * rsqrtf(var + 1e-5f);
    ss[c]      = sc;
    ss[HC + c] = beta[c] - mean * sc;
}

// finalize: BN affine + leaky(0.02), in place
__global__ __launch_bounds__(256) void k_final(float* __restrict__ out,
        const float* __restrict__ ss, int total) {
    int i = blockIdx.x * 256 + threadIdx.x;
    if (i >= total) return;
    int c = i & 127;
    float y = out[i] * ss[c] + ss[HC + c];
    out[i] = (y > 0.f) ? y : 0.02f * y;
}

extern "C" void kernel_launch(void* const* d_in, const int* in_sizes, int n_in,
                              void* d_out, int out_size, void* d_ws, size_t ws_size,
                              hipStream_t stream) {
    const float* x     = (const float*)d_in[0];
    const int*   ei    = (const int*)d_in[1];
    const float* Ws    = (const float*)d_in[2];
    const float* Wd    = (const float*)d_in[3];
    const float* att   = (const float*)d_in[4];
    // d_in[5] = bias: cancels exactly inside BatchNorm -> skipped
    const float* gamma = (const float*)d_in[6];
    const float* beta  = (const float*)d_in[7];
    float* out = (float*)d_out;

    int N  = in_sizes[0] / N_IN;
    int E  = in_sizes[1] / 2;
    int B  = (N + CHUNK - 1) / CHUNK;   // scan blocks (<=1024 supported)

    char* ws = (char*)d_ws;
    unsigned short* hs = (unsigned short*)ws; ws += (size_t)N * HC * 2;
    float* hd   = (float*)ws; ws += (size_t)N * HC * 4;
    int* deg    = (int*)ws;   ws += (size_t)N * 4;
    int* off    = (int*)ws;   ws += (size_t)N * 4;
    int* cur    = (int*)ws;   ws += (size_t)N * 4;
    int* ssrc   = (int*)ws;   ws += (size_t)E * 4;
    int* bsum   = (int*)ws;   ws += 1024 * 4;
    int* bsumx  = (int*)ws;   ws += 1024 * 4;
    float* stats= (float*)ws; ws += 2 * HC * 4;
    float* ss   = (float*)ws; ws += 2 * HC * 4;

    hipMemsetAsync(deg, 0, (size_t)N * 4, stream);
    hipMemsetAsync(stats, 0, 2 * HC * 4, stream);

    k_gemm<<<(N + NPB - 1) / NPB, 256, 0, stream>>>(x, Ws, Wd, hs, hd, N);
    k_hist<<<(E + 255) / 256, 256, 0, stream>>>(ei, deg, E);
    k_scan_part<<<B, 256, 0, stream>>>(deg, bsum, N);
    k_scan_mid<<<1, 1024, 0, stream>>>(bsum, bsumx, B);
    k_scan_add<<<B, 256, 0, stream>>>(deg, bsumx, off, cur, N);
    k_scatter<<<(E + 255) / 256, 256, 0, stream>>>(ei, cur, ssrc, E);
    k_agg2<<<(N * 64 + 255) / 256, 256, 0, stream>>>(hs, hd, off, deg, ssrc, att, out, N);
    k_stats<<<1024, 256, 0, stream>>>(out, stats, N);
    k_bnparams<<<1, 128, 0, stream>>>(stats, gamma, beta, ss, N);
    k_final<<<(N * HC + 255) / 256, 256, 0, stream>>>(out, ss, N * HC);
}

// Round 5
// 385.273 us; speedup vs baseline: 5.1627x; 1.2479x over previous
//
#include <hip/hip_runtime.h>
#include <math.h>

#define N_IN   128
#define HC     128   // HEADS*OUT_CH
#define HEADS  4
#define NPB    32    // nodes per block in GEMM
#define CHUNK  1024  // scan elements per block (256 thr x 4)
#define PB_T   4096  // edges per partition tile
#define PB_THR 512   // threads in k_part

// bf16 helpers: exact decode, RNE encode
__device__ __forceinline__ unsigned short f2bf(float f) {
    unsigned u = __float_as_uint(f);
    return (unsigned short)((u + 0x7FFFu + ((u >> 16) & 1u)) >> 16);
}
__device__ __forceinline__ float2 ldbf2(const unsigned short* p) {
    ushort2 u = *reinterpret_cast<const ushort2*>(p);
    float2 r;
    r.x = __uint_as_float((unsigned)u.x << 16);
    r.y = __uint_as_float((unsigned)u.y << 16);
    return r;
}

// h_src = x @ W_src, h_dst = x @ W_dst (both bf16 out)
__global__ __launch_bounds__(256) void k_gemm(const float* __restrict__ x,
        const float* __restrict__ Ws, const float* __restrict__ Wd,
        unsigned short* __restrict__ hs, unsigned short* __restrict__ hd, int N) {
    __shared__ float xs[NPB][N_IN];
    int nbase = blockIdx.x * NPB;
    for (int i = threadIdx.x; i < NPB * N_IN; i += 256) {
        int n = nbase + (i >> 7);
        xs[i >> 7][i & 127] = (n < N) ? x[(size_t)n * N_IN + (i & 127)] : 0.f;
    }
    __syncthreads();
    int cg = threadIdx.x & 63;
    int ng = threadIdx.x >> 6;
    bool is_src = (cg < 32);
    const float* W = is_src ? Ws : Wd;
    unsigned short* outp = is_src ? hs : hd;
    int c = (cg & 31) * 4;
    float acc[8][4];
#pragma unroll
    for (int n = 0; n < 8; n++) { acc[n][0]=0.f; acc[n][1]=0.f; acc[n][2]=0.f; acc[n][3]=0.f; }
    for (int k = 0; k < N_IN; k++) {
        float4 w = *reinterpret_cast<const float4*>(&W[k * HC + c]);
#pragma unroll
        for (int n = 0; n < 8; n++) {
            float xv = xs[ng * 8 + n][k];
            acc[n][0] += xv * w.x;
            acc[n][1] += xv * w.y;
            acc[n][2] += xv * w.z;
            acc[n][3] += xv * w.w;
        }
    }
#pragma unroll
    for (int n = 0; n < 8; n++) {
        int node = nbase + ng * 8 + n;
        if (node < N) {
            ushort4 b = make_ushort4(f2bf(acc[n][0]), f2bf(acc[n][1]),
                                     f2bf(acc[n][2]), f2bf(acc[n][3]));
            *reinterpret_cast<ushort4*>(&outp[(size_t)node * HC + c]) = b;
        }
    }
}

// in-degree histogram
__global__ __launch_bounds__(256) void k_hist(const int* __restrict__ ei,
        int* __restrict__ deg, int E) {
    int e = blockIdx.x * 256 + threadIdx.x;
    if (e < E) atomicAdd(&deg[ei[E + e]], 1);
}

// scan phase 1: per-block (1024-elem chunk) sum
__global__ __launch_bounds__(256) void k_scan_part(const int* __restrict__ deg,
        int* __restrict__ bsum, int N) {
    __shared__ int sh[256];
    int base = blockIdx.x * CHUNK + threadIdx.x * 4;
    int s = 0;
#pragma unroll
    for (int i = 0; i < 4; i++) s += (base + i < N) ? deg[base + i] : 0;
    sh[threadIdx.x] = s;
    __syncthreads();
    for (int ofs = 128; ofs > 0; ofs >>= 1) {
        if (threadIdx.x < ofs) sh[threadIdx.x] += sh[threadIdx.x + ofs];
        __syncthreads();
    }
    if (threadIdx.x == 0) bsum[blockIdx.x] = sh[0];
}

// scan phase 2: exclusive scan of block sums (single block)
__global__ __launch_bounds__(1024) void k_scan_mid(const int* __restrict__ bsum,
        int* __restrict__ bsumx, int B) {
    __shared__ int sh[1024];
    int t = threadIdx.x;
    int v = (t < B) ? bsum[t] : 0;
    sh[t] = v;
    __syncthreads();
    for (int ofs = 1; ofs < 1024; ofs <<= 1) {
        int add = (t >= ofs) ? sh[t - ofs] : 0;
        __syncthreads();
        sh[t] += add;
        __syncthreads();
    }
    if (t < B) bsumx[t] = sh[t] - v;   // exclusive
}

// scan phase 3: local prefix + block offset -> off
__global__ __launch_bounds__(256) void k_scan_add(const int* __restrict__ deg,
        const int* __restrict__ bsumx, int* __restrict__ off, int N) {
    __shared__ int sh[256];
    int t = threadIdx.x;
    int base = blockIdx.x * CHUNK + t * 4;
    int v0 = (base + 0 < N) ? deg[base + 0] : 0;
    int v1 = (base + 1 < N) ? deg[base + 1] : 0;
    int v2 = (base + 2 < N) ? deg[base + 2] : 0;
    int v3 = (base + 3 < N) ? deg[base + 3] : 0;
    int tot = v0 + v1 + v2 + v3;
    sh[t] = tot;
    __syncthreads();
    for (int ofs = 1; ofs < 256; ofs <<= 1) {
        int add = (t >= ofs) ? sh[t - ofs] : 0;
        __syncthreads();
        sh[t] += add;
        __syncthreads();
    }
    int run = sh[t] - tot + bsumx[blockIdx.x];
    int p0 = run, p1 = run + v0, p2 = p1 + v1, p3 = p2 + v2;
    if (base + 0 < N) off[base + 0] = p0;
    if (base + 1 < N) off[base + 1] = p1;
    if (base + 2 < N) off[base + 2] = p2;
    if (base + 3 < N) off[base + 3] = p3;
}

// bucket cursors init: bcur[b] = off[b<<8]
__global__ void k_binit(const int* __restrict__ off, int* __restrict__ bcur, int NB) {
    int b = blockIdx.x * 256 + threadIdx.x;
    if (b < NB) bcur[b] = off[b << 8];
}

// pass 1: LDS-staged partition of edges into 256-node dst-buckets.
// packed entry: (src<<8) | (dst & 255)   [src < 2^17, 256 nodes/bucket]
__global__ __launch_bounds__(PB_THR) void k_part(const int* __restrict__ ei,
        int* __restrict__ bcur, unsigned* __restrict__ ebuf, int E, int NB) {
    __shared__ int cnt[512], lscan[512], gbase[512], lcnt[512];
    __shared__ unsigned pr[PB_T];
    __shared__ unsigned short pb[PB_T];
    int t = threadIdx.x;
    int tb = blockIdx.x * PB_T;
    int tc = min(PB_T, E - tb);
    cnt[t] = 0; lcnt[t] = 0;
    __syncthreads();
    int dd[8], ss[8];
#pragma unroll
    for (int i = 0; i < 8; i++) {
        int e = tb + t + i * PB_THR;
        if (e < E) {
            ss[i] = ei[e];
            dd[i] = ei[E + e];
            atomicAdd(&cnt[dd[i] >> 8], 1);
        } else dd[i] = -1;
    }
    __syncthreads();
    lscan[t] = cnt[t];                       // inclusive scan
    __syncthreads();
    for (int ofs = 1; ofs < 512; ofs <<= 1) {
        int add = (t >= ofs) ? lscan[t - ofs] : 0;
        __syncthreads();
        lscan[t] += add;
        __syncthreads();
    }
    if (t < NB && cnt[t] > 0) gbase[t] = atomicAdd(&bcur[t], cnt[t]);
    __syncthreads();
#pragma unroll
    for (int i = 0; i < 8; i++) {
        if (dd[i] >= 0) {
            int b = dd[i] >> 8;
            int lpos = atomicAdd(&lcnt[b], 1);
            int j = lscan[b] - cnt[b] + lpos;
            pr[j] = ((unsigned)ss[i] << 8) | (unsigned)(dd[i] & 255);
            pb[j] = (unsigned short)b;
        }
    }
    __syncthreads();
    for (int k = t; k < tc; k += PB_THR) {
        int b = pb[k];
        ebuf[gbase[b] + k - (lscan[b] - cnt[b])] = pr[k];
    }
}

// pass 2: one block per bucket; LDS cursors; writes confined to a private window
__global__ __launch_bounds__(256) void k_place(const unsigned* __restrict__ ebuf,
        const int* __restrict__ off, int* __restrict__ ssrc, int N, int E) {
    __shared__ int lcur[256];
    int b = blockIdx.x;
    int nbase = b << 8;
    int t = threadIdx.x;
    int node = nbase + t;
    lcur[t] = (node < N) ? off[node] : 0;
    __syncthreads();
    int rbeg = off[nbase];
    int nend = nbase + 256;
    int rend = (nend < N) ? off[nend] : E;
    int k = rbeg + t;
    for (; k + 256 < rend; k += 512) {
        unsigned u0 = ebuf[k], u1 = ebuf[k + 256];
        int p0 = atomicAdd(&lcur[u0 & 255u], 1);
        int p1 = atomicAdd(&lcur[u1 & 255u], 1);
        ssrc[p0] = (int)(u0 >> 8);
        ssrc[p1] = (int)(u1 >> 8);
    }
    if (k < rend) {
        unsigned u = ebuf[k];
        int p = atomicAdd(&lcur[u & 255u], 1);
        ssrc[p] = (int)(u >> 8);
    }
}

// ---- fused per-node aggregation --------------------------------------------
__device__ __forceinline__ float edge_logit(float2 v, float2 hdv, float2 at) {
    float t0 = v.x + hdv.x; t0 = (t0 > 0.f) ? t0 : 0.2f * t0;
    float t1 = v.y + hdv.y; t1 = (t1 > 0.f) ? t1 : 0.2f * t1;
    float p = t0 * at.x + t1 * at.y;
    p += __shfl_xor(p, 1); p += __shfl_xor(p, 2);
    p += __shfl_xor(p, 4); p += __shfl_xor(p, 8);
    return p;
}
__device__ __forceinline__ void sm_merge(float2 v, float p,
        float& m, float& ssum, float2& acc) {
    float nm = fmaxf(m, p);
    float r = __expf(m - nm);
    float e = __expf(p - nm);
    ssum = ssum * r + e;
    acc.x = acc.x * r + e * v.x;
    acc.y = acc.y * r + e * v.y;
    m = nm;
}

// one wave per node; lane -> 2 channels; head = lane>>4. bf16 gathers.
__global__ __launch_bounds__(256) void k_agg2(const unsigned short* __restrict__ hs,
        const unsigned short* __restrict__ hd, const int* __restrict__ off,
        const int* __restrict__ deg, const int* __restrict__ ssrc,
        const float* __restrict__ att, float* __restrict__ out, int N) {
    int wid = (blockIdx.x * 256 + threadIdx.x) >> 6;
    int lane = threadIdx.x & 63;
    if (wid >= N) return;
    int c2 = lane * 2;
    float2 at  = *reinterpret_cast<const float2*>(&att[c2]);
    float2 hdv = ldbf2(&hd[(size_t)wid * HC + c2]);
    float2 v = ldbf2(&hs[(size_t)wid * HC + c2]);
    float m = edge_logit(v, hdv, at);
    float ssum = 1.f;
    float2 acc = v;
    int beg = off[wid], end = beg + deg[wid];
    int i = beg;
    for (; i + 3 < end; i += 4) {
        int s0 = ssrc[i], s1 = ssrc[i + 1], s2 = ssrc[i + 2], s3 = ssrc[i + 3];
        float2 v0 = ldbf2(&hs[(size_t)s0 * HC + c2]);
        float2 v1 = ldbf2(&hs[(size_t)s1 * HC + c2]);
        float2 v2 = ldbf2(&hs[(size_t)s2 * HC + c2]);
        float2 v3 = ldbf2(&hs[(size_t)s3 * HC + c2]);
        float p0 = edge_logit(v0, hdv, at);
        float p1 = edge_logit(v1, hdv, at);
        float p2 = edge_logit(v2, hdv, at);
        float p3 = edge_logit(v3, hdv, at);
        sm_merge(v0, p0, m, ssum, acc);
        sm_merge(v1, p1, m, ssum, acc);
        sm_merge(v2, p2, m, ssum, acc);
        sm_merge(v3, p3, m, ssum, acc);
    }
    for (; i < end; i++) {
        int s = ssrc[i];
        float2 ve = ldbf2(&hs[(size_t)s * HC + c2]);
        float pe = edge_logit(ve, hdv, at);
        sm_merge(ve, pe, m, ssum, acc);
    }
    float inv = 1.f / ssum;
    *reinterpret_cast<float2*>(&out[(size_t)wid * HC + c2]) =
        make_float2(acc.x * inv, acc.y * inv);
}

// per-channel sum & sumsq of pre-BN values
__global__ __launch_bounds__(256) void k_stats(const float* __restrict__ out,
        float* __restrict__ stats, int N) {
    int ch = threadIdx.x & 127;
    int half = threadIdx.x >> 7;
    float s = 0.f, s2 = 0.f;
    for (int n = blockIdx.x * 2 + half; n < N; n += gridDim.x * 2) {
        float v = out[(size_t)n * HC + ch];
        s += v; s2 += v * v;
    }
    __shared__ float sh[2][256];
    sh[0][threadIdx.x] = s; sh[1][threadIdx.x] = s2;
    __syncthreads();
    if (threadIdx.x < 128) {
        atomicAdd(&stats[ch],      sh[0][threadIdx.x] + sh[0][threadIdx.x + 128]);
        atomicAdd(&stats[HC + ch], sh[1][threadIdx.x] + sh[1][threadIdx.x + 128]);
    }
}

// fold stats into scale/shift
__global__ void k_bnparams(const float* __restrict__ stats,
        const float* __restrict__ gamma, const float* __restrict__ beta,
        float* __restrict__ ss, int N) {
    int c = threadIdx.x;
    if (c >= HC) return;
    float mean = stats[c] / (float)N;
    float var  = stats[HC + c] / (float)N - mean * mean;
    float sc = gamma[c] * rsqrtf(var + 1e-5f);
    ss[c]      = sc;
    ss[HC + c] = beta[c] - mean * sc;
}

// finalize: BN affine + leaky(0.02), in place
__global__ __launch_bounds__(256) void k_final(float* __restrict__ out,
        const float* __restrict__ ss, int total) {
    int i = blockIdx.x * 256 + threadIdx.x;
    if (i >= total) return;
    int c = i & 127;
    float y = out[i] * ss[c] + ss[HC + c];
    out[i] = (y > 0.f) ? y : 0.02f * y;
}

extern "C" void kernel_launch(void* const* d_in, const int* in_sizes, int n_in,
                              void* d_out, int out_size, void* d_ws, size_t ws_size,
                              hipStream_t stream) {
    const float* x     = (const float*)d_in[0];
    const int*   ei    = (const int*)d_in[1];
    const float* Ws    = (const float*)d_in[2];
    const float* Wd    = (const float*)d_in[3];
    const float* att   = (const float*)d_in[4];
    // d_in[5] = bias: cancels exactly inside BatchNorm -> skipped
    const float* gamma = (const float*)d_in[6];
    const float* beta  = (const float*)d_in[7];
    float* out = (float*)d_out;

    int N  = in_sizes[0] / N_IN;
    int E  = in_sizes[1] / 2;
    int B  = (N + CHUNK - 1) / CHUNK;   // scan blocks
    int NB = (N + 255) >> 8;            // dst buckets (256 nodes each)

    char* ws = (char*)d_ws;
    unsigned short* hs = (unsigned short*)ws; ws += (size_t)N * HC * 2;
    unsigned short* hd = (unsigned short*)ws; ws += (size_t)N * HC * 2;
    int* deg    = (int*)ws;      ws += (size_t)N * 4;
    int* off    = (int*)ws;      ws += (size_t)N * 4;
    unsigned* ebuf = (unsigned*)ws; ws += (size_t)E * 4;
    int* ssrc   = (int*)ws;      ws += (size_t)E * 4;
    int* bcur   = (int*)ws;      ws += (size_t)NB * 4;
    int* bsum   = (int*)ws;      ws += 1024 * 4;
    int* bsumx  = (int*)ws;      ws += 1024 * 4;
    float* stats= (float*)ws;    ws += 2 * HC * 4;
    float* ss   = (float*)ws;    ws += 2 * HC * 4;

    hipMemsetAsync(deg, 0, (size_t)N * 4, stream);
    hipMemsetAsync(stats, 0, 2 * HC * 4, stream);

    k_gemm<<<(N + NPB - 1) / NPB, 256, 0, stream>>>(x, Ws, Wd, hs, hd, N);
    k_hist<<<(E + 255) / 256, 256, 0, stream>>>(ei, deg, E);
    k_scan_part<<<B, 256, 0, stream>>>(deg, bsum, N);
    k_scan_mid<<<1, 1024, 0, stream>>>(bsum, bsumx, B);
    k_scan_add<<<B, 256, 0, stream>>>(deg, bsumx, off, N);
    k_binit<<<(NB + 255) / 256, 256, 0, stream>>>(off, bcur, NB);
    k_part<<<(E + PB_T - 1) / PB_T, PB_THR, 0, stream>>>(ei, bcur, ebuf, E, NB);
    k_place<<<NB, 256, 0, stream>>>(ebuf, off, ssrc, N, E);
    k_agg2<<<(N * 64 + 255) / 256, 256, 0, stream>>>(hs, hd, off, deg, ssrc, att, out, N);
    k_stats<<<1024, 256, 0, stream>>>(out, stats, N);
    k_bnparams<<<1, 128, 0, stream>>>(stats, gamma, beta, ss, N);
    k_final<<<(N * HC + 255) / 256, 256, 0, stream>>>(out, ss, N * HC);
}

// Round 6
// 343.146 us; speedup vs baseline: 5.7965x; 1.1228x over previous
//
#include <hip/hip_runtime.h>
#include <math.h>

#define N_IN   128
#define HC     128   // HEADS*OUT_CH
#define HEADS  4
#define CHUNK  1024  // scan elements per block (256 thr x 4)
#define PB_T   4096  // edges per partition tile
#define PB_THR 512   // threads in k_part

typedef __attribute__((ext_vector_type(8))) short bf16x8;
typedef __attribute__((ext_vector_type(4))) float f32x4;

// bf16 helpers: exact decode, RNE encode
__device__ __forceinline__ unsigned short f2bf(float f) {
    unsigned u = __float_as_uint(f);
    return (unsigned short)((u + 0x7FFFu + ((u >> 16) & 1u)) >> 16);
}
__device__ __forceinline__ float2 ldbf2(const unsigned short* p) {
    ushort2 u = *reinterpret_cast<const ushort2*>(p);
    float2 r;
    r.x = __uint_as_float((unsigned)u.x << 16);
    r.y = __uint_as_float((unsigned)u.y << 16);
    return r;
}

// prep: Wt[n][k] = bf16( n<128 ? Ws[k][n] : Wd[k][n-128] )   (Wt: [256][128])
__global__ __launch_bounds__(256) void k_prep(const float* __restrict__ Ws,
        const float* __restrict__ Wd, unsigned short* __restrict__ Wt) {
    int i = blockIdx.x * 256 + threadIdx.x;   // i = n*128 + k
    if (i >= 256 * 128) return;
    int n = i >> 7, k = i & 127;
    float v = (n < 128) ? Ws[k * HC + n] : Wd[k * HC + (n - 128)];
    Wt[i] = f2bf(v);
}

// MFMA GEMM: [N x 128] @ [128 x 256] -> hs (cols 0..127), hd (cols 128..255), bf16
// block = 4 waves = 32 rows; wave owns 64 cols (4 col-tiles of 16).
__global__ __launch_bounds__(256) void k_gemm(const float* __restrict__ x,
        const unsigned short* __restrict__ Wt,
        unsigned short* __restrict__ hs, unsigned short* __restrict__ hd, int N) {
    int wave = threadIdx.x >> 6, lane = threadIdx.x & 63;
    int colbase = wave * 64;
    int rowbase = blockIdx.x * 32;
    int lr = lane & 15;    // row (A) / col (B,D) within tile
    int lg = lane >> 4;    // k-group (A,B) / row-group (D)

    // B fragments: B[k = lg*8+j][col = colbase+ct*16+lr], 8 contiguous bf16 in Wt
    bf16x8 b[4][4];
#pragma unroll
    for (int ct = 0; ct < 4; ct++)
#pragma unroll
        for (int kk = 0; kk < 4; kk++)
            b[ct][kk] = *reinterpret_cast<const bf16x8*>(
                &Wt[(size_t)(colbase + ct * 16 + lr) * 128 + kk * 32 + lg * 8]);

    f32x4 acc[2][4];
#pragma unroll
    for (int rt = 0; rt < 2; rt++)
#pragma unroll
        for (int ct = 0; ct < 4; ct++)
            acc[rt][ct] = (f32x4){0.f, 0.f, 0.f, 0.f};

#pragma unroll
    for (int rt = 0; rt < 2; rt++) {
        int row = rowbase + rt * 16 + lr;
        const float* xr = &x[(size_t)row * N_IN];
        bool ok = (row < N);
#pragma unroll
        for (int kk = 0; kk < 4; kk++) {
            f32x4 xa = (f32x4){0.f, 0.f, 0.f, 0.f}, xb = xa;
            if (ok) {
                xa = *reinterpret_cast<const f32x4*>(&xr[kk * 32 + lg * 8]);
                xb = *reinterpret_cast<const f32x4*>(&xr[kk * 32 + lg * 8 + 4]);
            }
            bf16x8 a;
            a[0] = (short)f2bf(xa[0]); a[1] = (short)f2bf(xa[1]);
            a[2] = (short)f2bf(xa[2]); a[3] = (short)f2bf(xa[3]);
            a[4] = (short)f2bf(xb[0]); a[5] = (short)f2bf(xb[1]);
            a[6] = (short)f2bf(xb[2]); a[7] = (short)f2bf(xb[3]);
#pragma unroll
            for (int ct = 0; ct < 4; ct++)
                acc[rt][ct] = __builtin_amdgcn_mfma_f32_16x16x32_bf16(
                    a, b[ct][kk], acc[rt][ct], 0, 0, 0);
        }
    }

    // store: D row=(lg*4+i), col=lr within tile
#pragma unroll
    for (int rt = 0; rt < 2; rt++) {
#pragma unroll
        for (int ct = 0; ct < 4; ct++) {
            int col = colbase + ct * 16 + lr;
            unsigned short* outp = (col < HC) ? hs : hd;
            int cc = col & (HC - 1);
#pragma unroll
            for (int i = 0; i < 4; i++) {
                int row = rowbase + rt * 16 + lg * 4 + i;
                if (row < N) outp[(size_t)row * HC + cc] = f2bf(acc[rt][ct][i]);
            }
        }
    }
}

// in-degree histogram
__global__ __launch_bounds__(256) void k_hist(const int* __restrict__ ei,
        int* __restrict__ deg, int E) {
    int e = blockIdx.x * 256 + threadIdx.x;
    if (e < E) atomicAdd(&deg[ei[E + e]], 1);
}

// scan phase 1: per-block (1024-elem chunk) sum
__global__ __launch_bounds__(256) void k_scan_part(const int* __restrict__ deg,
        int* __restrict__ bsum, int N) {
    __shared__ int sh[256];
    int base = blockIdx.x * CHUNK + threadIdx.x * 4;
    int s = 0;
#pragma unroll
    for (int i = 0; i < 4; i++) s += (base + i < N) ? deg[base + i] : 0;
    sh[threadIdx.x] = s;
    __syncthreads();
    for (int ofs = 128; ofs > 0; ofs >>= 1) {
        if (threadIdx.x < ofs) sh[threadIdx.x] += sh[threadIdx.x + ofs];
        __syncthreads();
    }
    if (threadIdx.x == 0) bsum[blockIdx.x] = sh[0];
}

// scan phase 2: exclusive scan of block sums (single block)
__global__ __launch_bounds__(1024) void k_scan_mid(const int* __restrict__ bsum,
        int* __restrict__ bsumx, int B) {
    __shared__ int sh[1024];
    int t = threadIdx.x;
    int v = (t < B) ? bsum[t] : 0;
    sh[t] = v;
    __syncthreads();
    for (int ofs = 1; ofs < 1024; ofs <<= 1) {
        int add = (t >= ofs) ? sh[t - ofs] : 0;
        __syncthreads();
        sh[t] += add;
        __syncthreads();
    }
    if (t < B) bsumx[t] = sh[t] - v;   // exclusive
}

// scan phase 3: local prefix + block offset -> off
__global__ __launch_bounds__(256) void k_scan_add(const int* __restrict__ deg,
        const int* __restrict__ bsumx, int* __restrict__ off, int N) {
    __shared__ int sh[256];
    int t = threadIdx.x;
    int base = blockIdx.x * CHUNK + t * 4;
    int v0 = (base + 0 < N) ? deg[base + 0] : 0;
    int v1 = (base + 1 < N) ? deg[base + 1] : 0;
    int v2 = (base + 2 < N) ? deg[base + 2] : 0;
    int v3 = (base + 3 < N) ? deg[base + 3] : 0;
    int tot = v0 + v1 + v2 + v3;
    sh[t] = tot;
    __syncthreads();
    for (int ofs = 1; ofs < 256; ofs <<= 1) {
        int add = (t >= ofs) ? sh[t - ofs] : 0;
        __syncthreads();
        sh[t] += add;
        __syncthreads();
    }
    int run = sh[t] - tot + bsumx[blockIdx.x];
    int p0 = run, p1 = run + v0, p2 = p1 + v1, p3 = p2 + v2;
    if (base + 0 < N) off[base + 0] = p0;
    if (base + 1 < N) off[base + 1] = p1;
    if (base + 2 < N) off[base + 2] = p2;
    if (base + 3 < N) off[base + 3] = p3;
}

// bucket cursors init: bcur[b] = off[b<<8]
__global__ void k_binit(const int* __restrict__ off, int* __restrict__ bcur, int NB) {
    int b = blockIdx.x * 256 + threadIdx.x;
    if (b < NB) bcur[b] = off[b << 8];
}

// pass 1: LDS-staged partition of edges into 256-node dst-buckets.
// packed entry: (src<<8) | (dst & 255)   [src < 2^17, 256 nodes/bucket]
__global__ __launch_bounds__(PB_THR) void k_part(const int* __restrict__ ei,
        int* __restrict__ bcur, unsigned* __restrict__ ebuf, int E, int NB) {
    __shared__ int cnt[512], lscan[512], gbase[512], lcnt[512];
    __shared__ unsigned pr[PB_T];
    __shared__ unsigned short pb[PB_T];
    int t = threadIdx.x;
    int tb = blockIdx.x * PB_T;
    int tc = min(PB_T, E - tb);
    cnt[t] = 0; lcnt[t] = 0;
    __syncthreads();
    int dd[8], ss[8];
#pragma unroll
    for (int i = 0; i < 8; i++) {
        int e = tb + t + i * PB_THR;
        if (e < E) {
            ss[i] = ei[e];
            dd[i] = ei[E + e];
            atomicAdd(&cnt[dd[i] >> 8], 1);
        } else dd[i] = -1;
    }
    __syncthreads();
    lscan[t] = cnt[t];                       // inclusive scan
    __syncthreads();
    for (int ofs = 1; ofs < 512; ofs <<= 1) {
        int add = (t >= ofs) ? lscan[t - ofs] : 0;
        __syncthreads();
        lscan[t] += add;
        __syncthreads();
    }
    if (t < NB && cnt[t] > 0) gbase[t] = atomicAdd(&bcur[t], cnt[t]);
    __syncthreads();
#pragma unroll
    for (int i = 0; i < 8; i++) {
        if (dd[i] >= 0) {
            int b = dd[i] >> 8;
            int lpos = atomicAdd(&lcnt[b], 1);
            int j = lscan[b] - cnt[b] + lpos;
            pr[j] = ((unsigned)ss[i] << 8) | (unsigned)(dd[i] & 255);
            pb[j] = (unsigned short)b;
        }
    }
    __syncthreads();
    for (int k = t; k < tc; k += PB_THR) {
        int b = pb[k];
        ebuf[gbase[b] + k - (lscan[b] - cnt[b])] = pr[k];
    }
}

// pass 2: one block per bucket; LDS cursors; writes confined to a private window
__global__ __launch_bounds__(256) void k_place(const unsigned* __restrict__ ebuf,
        const int* __restrict__ off, int* __restrict__ ssrc, int N, int E) {
    __shared__ int lcur[256];
    int b = blockIdx.x;
    int nbase = b << 8;
    int t = threadIdx.x;
    int node = nbase + t;
    lcur[t] = (node < N) ? off[node] : 0;
    __syncthreads();
    int rbeg = off[nbase];
    int nend = nbase + 256;
    int rend = (nend < N) ? off[nend] : E;
    int k = rbeg + t;
    for (; k + 256 < rend; k += 512) {
        unsigned u0 = ebuf[k], u1 = ebuf[k + 256];
        int p0 = atomicAdd(&lcur[u0 & 255u], 1);
        int p1 = atomicAdd(&lcur[u1 & 255u], 1);
        ssrc[p0] = (int)(u0 >> 8);
        ssrc[p1] = (int)(u1 >> 8);
    }
    if (k < rend) {
        unsigned u = ebuf[k];
        int p = atomicAdd(&lcur[u & 255u], 1);
        ssrc[p] = (int)(u >> 8);
    }
}

// ---- fused per-node aggregation --------------------------------------------
__device__ __forceinline__ float edge_logit(float2 v, float2 hdv, float2 at) {
    float t0 = v.x + hdv.x; t0 = (t0 > 0.f) ? t0 : 0.2f * t0;
    float t1 = v.y + hdv.y; t1 = (t1 > 0.f) ? t1 : 0.2f * t1;
    float p = t0 * at.x + t1 * at.y;
    p += __shfl_xor(p, 1); p += __shfl_xor(p, 2);
    p += __shfl_xor(p, 4); p += __shfl_xor(p, 8);
    return p;
}
__device__ __forceinline__ void sm_merge(float2 v, float p,
        float& m, float& ssum, float2& acc) {
    float nm = fmaxf(m, p);
    float r = __expf(m - nm);
    float e = __expf(p - nm);
    ssum = ssum * r + e;
    acc.x = acc.x * r + e * v.x;
    acc.y = acc.y * r + e * v.y;
    m = nm;
}

// one wave per node; lane -> 2 channels; head = lane>>4. bf16 gathers.
__global__ __launch_bounds__(256) void k_agg2(const unsigned short* __restrict__ hs,
        const unsigned short* __restrict__ hd, const int* __restrict__ off,
        const int* __restrict__ deg, const int* __restrict__ ssrc,
        const float* __restrict__ att, float* __restrict__ out, int N) {
    int wid = (blockIdx.x * 256 + threadIdx.x) >> 6;
    int lane = threadIdx.x & 63;
    if (wid >= N) return;
    int c2 = lane * 2;
    float2 at  = *reinterpret_cast<const float2*>(&att[c2]);
    float2 hdv = ldbf2(&hd[(size_t)wid * HC + c2]);
    float2 v = ldbf2(&hs[(size_t)wid * HC + c2]);
    float m = edge_logit(v, hdv, at);
    float ssum = 1.f;
    float2 acc = v;
    int beg = off[wid], end = beg + deg[wid];
    int i = beg;
    for (; i + 3 < end; i += 4) {
        int s0 = ssrc[i], s1 = ssrc[i + 1], s2 = ssrc[i + 2], s3 = ssrc[i + 3];
        float2 v0 = ldbf2(&hs[(size_t)s0 * HC + c2]);
        float2 v1 = ldbf2(&hs[(size_t)s1 * HC + c2]);
        float2 v2 = ldbf2(&hs[(size_t)s2 * HC + c2]);
        float2 v3 = ldbf2(&hs[(size_t)s3 * HC + c2]);
        float p0 = edge_logit(v0, hdv, at);
        float p1 = edge_logit(v1, hdv, at);
        float p2 = edge_logit(v2, hdv, at);
        float p3 = edge_logit(v3, hdv, at);
        sm_merge(v0, p0, m, ssum, acc);
        sm_merge(v1, p1, m, ssum, acc);
        sm_merge(v2, p2, m, ssum, acc);
        sm_merge(v3, p3, m, ssum, acc);
    }
    for (; i < end; i++) {
        int s = ssrc[i];
        float2 ve = ldbf2(&hs[(size_t)s * HC + c2]);
        float pe = edge_logit(ve, hdv, at);
        sm_merge(ve, pe, m, ssum, acc);
    }
    float inv = 1.f / ssum;
    *reinterpret_cast<float2*>(&out[(size_t)wid * HC + c2]) =
        make_float2(acc.x * inv, acc.y * inv);
}

// per-channel sum & sumsq of pre-BN values
__global__ __launch_bounds__(256) void k_stats(const float* __restrict__ out,
        float* __restrict__ stats, int N) {
    int ch = threadIdx.x & 127;
    int half = threadIdx.x >> 7;
    float s = 0.f, s2 = 0.f;
    for (int n = blockIdx.x * 2 + half; n < N; n += gridDim.x * 2) {
        float v = out[(size_t)n * HC + ch];
        s += v; s2 += v * v;
    }
    __shared__ float sh[2][256];
    sh[0][threadIdx.x] = s; sh[1][threadIdx.x] = s2;
    __syncthreads();
    if (threadIdx.x < 128) {
        atomicAdd(&stats[ch],      sh[0][threadIdx.x] + sh[0][threadIdx.x + 128]);
        atomicAdd(&stats[HC + ch], sh[1][threadIdx.x] + sh[1][threadIdx.x + 128]);
    }
}

// fold stats into scale/shift
__global__ void k_bnparams(const float* __restrict__ stats,
        const float* __restrict__ gamma, const float* __restrict__ beta,
        float* __restrict__ ss, int N) {
    int c = threadIdx.x;
    if (c >= HC) return;
    float mean = stats[c] / (float)N;
    float var  = stats[HC + c] / (float)N - mean * mean;
    float sc = gamma[c] * rsqrtf(var + 1e-5f);
    ss[c]      = sc;
    ss[HC + c] = beta[c] - mean * sc;
}

// finalize: BN affine + leaky(0.02), in place
__global__ __launch_bounds__(256) void k_final(float* __restrict__ out,
        const float* __restrict__ ss, int total) {
    int i = blockIdx.x * 256 + threadIdx.x;
    if (i >= total) return;
    int c = i & 127;
    float y = out[i] * ss[c] + ss[HC + c];
    out[i] = (y > 0.f) ? y : 0.02f * y;
}

extern "C" void kernel_launch(void* const* d_in, const int* in_sizes, int n_in,
                              void* d_out, int out_size, void* d_ws, size_t ws_size,
                              hipStream_t stream) {
    const float* x     = (const float*)d_in[0];
    const int*   ei    = (const int*)d_in[1];
    const float* Ws    = (const float*)d_in[2];
    const float* Wd    = (const float*)d_in[3];
    const float* att   = (const float*)d_in[4];
    // d_in[5] = bias: cancels exactly inside BatchNorm -> skipped
    const float* gamma = (const float*)d_in[6];
    const float* beta  = (const float*)d_in[7];
    float* out = (float*)d_out;

    int N  = in_sizes[0] / N_IN;
    int E  = in_sizes[1] / 2;
    int B  = (N + CHUNK - 1) / CHUNK;   // scan blocks
    int NB = (N + 255) >> 8;            // dst buckets (256 nodes each)

    char* ws = (char*)d_ws;
    unsigned short* hs = (unsigned short*)ws; ws += (size_t)N * HC * 2;
    unsigned short* hd = (unsigned short*)ws; ws += (size_t)N * HC * 2;
    int* deg    = (int*)ws;      ws += (size_t)N * 4;
    int* off    = (int*)ws;      ws += (size_t)N * 4;
    unsigned* ebuf = (unsigned*)ws; ws += (size_t)E * 4;
    int* ssrc   = (int*)ws;      ws += (size_t)E * 4;
    int* bcur   = (int*)ws;      ws += (size_t)NB * 4;
    int* bsum   = (int*)ws;      ws += 1024 * 4;
    int* bsumx  = (int*)ws;      ws += 1024 * 4;
    unsigned short* Wt = (unsigned short*)ws; ws += 256 * 128 * 2;
    float* stats= (float*)ws;    ws += 2 * HC * 4;
    float* ss   = (float*)ws;    ws += 2 * HC * 4;

    hipMemsetAsync(deg, 0, (size_t)N * 4, stream);
    hipMemsetAsync(stats, 0, 2 * HC * 4, stream);

    k_prep<<<128, 256, 0, stream>>>(Ws, Wd, Wt);
    k_gemm<<<(N + 31) / 32, 256, 0, stream>>>(x, Wt, hs, hd, N);
    k_hist<<<(E + 255) / 256, 256, 0, stream>>>(ei, deg, E);
    k_scan_part<<<B, 256, 0, stream>>>(deg, bsum, N);
    k_scan_mid<<<1, 1024, 0, stream>>>(bsum, bsumx, B);
    k_scan_add<<<B, 256, 0, stream>>>(deg, bsumx, off, N);
    k_binit<<<(NB + 255) / 256, 256, 0, stream>>>(off, bcur, NB);
    k_part<<<(E + PB_T - 1) / PB_T, PB_THR, 0, stream>>>(ei, bcur, ebuf, E, NB);
    k_place<<<NB, 256, 0, stream>>>(ebuf, off, ssrc, N, E);
    k_agg2<<<(N * 64 + 255) / 256, 256, 0, stream>>>(hs, hd, off, deg, ssrc, att, out, N);
    k_stats<<<1024, 256, 0, stream>>>(out, stats, N);
    k_bnparams<<<1, 128, 0, stream>>>(stats, gamma, beta, ss, N);
    k_final<<<(N * HC + 255) / 256, 256, 0, stream>>>(out, ss, N * HC);
}